// Round 3
// baseline (382.091 us; speedup 1.0000x reference)
//
#include <hip/hip_runtime.h>

typedef unsigned short ushort_t;
typedef __attribute__((ext_vector_type(8))) unsigned short ushort8;
typedef __attribute__((ext_vector_type(8))) short bf16x8;
typedef __attribute__((ext_vector_type(4))) float f32x4;

#define BB 64
#define II 512
#define DD 128
#define NN 32
#define OO 64

__device__ inline ushort_t f2bf(float f) {
  unsigned int u = __float_as_uint(f);
  u += 0x7FFF + ((u >> 16) & 1);   // RNE
  return (ushort_t)(u >> 16);
}
__device__ inline float bf2f(ushort_t h) {
  return __uint_as_float(((unsigned int)h) << 16);
}

// load 8 contiguous u-elements as fp32
__device__ inline void load8u(const float* p, float* a) {
  f32x4 v0 = *(const f32x4*)p;
  f32x4 v1 = *(const f32x4*)(p + 4);
  a[0]=v0[0]; a[1]=v0[1]; a[2]=v0[2]; a[3]=v0[3];
  a[4]=v1[0]; a[5]=v1[1]; a[6]=v1[2]; a[7]=v1[3];
}
__device__ inline void load8u(const ushort_t* p, float* a) {
  ushort8 v = *(const ushort8*)p;
  #pragma unroll
  for (int e = 0; e < 8; ++e) a[e] = bf2f(v[e]);
}

// ---------------------------------------------------------------------------
// K1: u[b,n,i,o] = sum_d x[b,i,d] * W[n,i,o,d], fp32-accurate via split-bf16:
// u = xh*Wh + xl*Wh + xh*Wl (3 MFMAs). WG = (i, n-block of 8).
// (validated round 2: first-call absmax 0.5)
// ---------------------------------------------------------------------------
template<typename UT>
__global__ __launch_bounds__(256) void k_compute_u(
    const float* __restrict__ x, const float* __restrict__ W,
    UT* __restrict__ u)
{
  __shared__ ushort_t Ah[64*128] __attribute__((aligned(16)));
  __shared__ ushort_t Al[64*128] __attribute__((aligned(16)));
  __shared__ ushort_t Bh[64*128] __attribute__((aligned(16)));
  __shared__ ushort_t Bl[64*128] __attribute__((aligned(16)));
  __shared__ float    Cs[64*64]  __attribute__((aligned(16)));
  const int tid  = threadIdx.x;
  const int i    = blockIdx.x;
  const int n0   = blockIdx.y * 8;
  const int w    = tid >> 6;
  const int lane = tid & 63;

  // stage A = x[:, i, :]  (64 b-rows x 128 d), fp32 -> bf16 hi+lo
  for (int k = 0; k < 4; ++k) {
    int flat = tid + 256*k;      // 1024 chunks of 8 floats
    int row  = flat >> 4;
    int c8   = flat & 15;
    const float* gp = x + ((size_t)row*II + i)*DD + c8*8;
    float4 f0 = *(const float4*)(gp);
    float4 f1 = *(const float4*)(gp + 4);
    float fv[8] = {f0.x,f0.y,f0.z,f0.w,f1.x,f1.y,f1.z,f1.w};
    ushort8 h, l;
    #pragma unroll
    for (int e = 0; e < 8; ++e) {
      ushort_t hh = f2bf(fv[e]); h[e] = hh; l[e] = f2bf(fv[e] - bf2f(hh));
    }
    int off = (row*256 + c8*16) ^ ((row & 7) << 4);
    *(ushort8*)((char*)Ah + off) = h;
    *(ushort8*)((char*)Al + off) = l;
  }

  for (int j = 0; j < 8; ++j) {
    int n = n0 + j;
    __syncthreads();  // A staged (j==0); prev iter's Cs->u store done (j>0)

    // stage B = W[n, i, :, :]  (64 o-rows x 128 d), hi+lo
    const float* wbase = W + (((size_t)n*II + i)*OO)*DD;
    for (int k = 0; k < 4; ++k) {
      int flat = tid + 256*k;
      int row  = flat >> 4;
      int c8   = flat & 15;
      const float* gp = wbase + row*DD + c8*8;
      float4 f0 = *(const float4*)(gp);
      float4 f1 = *(const float4*)(gp + 4);
      float fv[8] = {f0.x,f0.y,f0.z,f0.w,f1.x,f1.y,f1.z,f1.w};
      ushort8 h, l;
      #pragma unroll
      for (int e = 0; e < 8; ++e) {
        ushort_t hh = f2bf(fv[e]); h[e] = hh; l[e] = f2bf(fv[e] - bf2f(hh));
      }
      int off = (row*256 + c8*16) ^ ((row & 7) << 4);
      *(ushort8*)((char*)Bh + off) = h;
      *(ushort8*)((char*)Bl + off) = l;
    }
    __syncthreads();

    f32x4 zero = {0.f, 0.f, 0.f, 0.f};
    f32x4 acc[4];
    #pragma unroll
    for (int ot = 0; ot < 4; ++ot) acc[ot] = zero;

    #pragma unroll
    for (int kk = 0; kk < 4; ++kk) {
      int ra   = w*16 + (lane & 15);
      int aoff = (ra*256 + kk*64 + ((lane >> 4) << 4)) ^ ((ra & 7) << 4);
      bf16x8 ah = *(bf16x8*)((char*)Ah + aoff);
      bf16x8 al = *(bf16x8*)((char*)Al + aoff);
      #pragma unroll
      for (int ot = 0; ot < 4; ++ot) {
        int rb   = ot*16 + (lane & 15);
        int boff = (rb*256 + kk*64 + ((lane >> 4) << 4)) ^ ((rb & 7) << 4);
        bf16x8 bh = *(bf16x8*)((char*)Bh + boff);
        bf16x8 bl = *(bf16x8*)((char*)Bl + boff);
        acc[ot] = __builtin_amdgcn_mfma_f32_16x16x32_bf16(ah, bh, acc[ot], 0, 0, 0);
        acc[ot] = __builtin_amdgcn_mfma_f32_16x16x32_bf16(al, bh, acc[ot], 0, 0, 0);
        acc[ot] = __builtin_amdgcn_mfma_f32_16x16x32_bf16(ah, bl, acc[ot], 0, 0, 0);
      }
    }

    // D lane map: col = lane&15, row = (lane>>4)*4 + r  (m89-verified)
    #pragma unroll
    for (int ot = 0; ot < 4; ++ot)
      #pragma unroll
      for (int r = 0; r < 4; ++r) {
        int row = w*16 + ((lane >> 4) << 2) + r;
        int col = ot*16 + (lane & 15);
        Cs[row*64 + col] = acc[ot][r];
      }
    __syncthreads();

    // coalesced store Cs -> u[b, n, i, :]
    for (int k = 0; k < 2; ++k) {
      int flat = tid + 256*k;   // 512 chunks of 8
      int row  = flat >> 3;     // b
      int c8   = flat & 7;
      const float* sp = Cs + row*64 + c8*8;
      UT* dst = u + (((size_t)row*NN + n)*II + i)*OO + c8*8;
      if constexpr (sizeof(UT) == 4) {
        *(f32x4*)dst       = *(const f32x4*)sp;
        *(f32x4*)(dst + 4) = *(const f32x4*)(sp + 4);
      } else {
        ushort8 v;
        #pragma unroll
        for (int e = 0; e < 8; ++e) v[e] = f2bf(sp[e]);
        *(ushort8*)dst = v;
      }
    }
  }
}

// ---------------------------------------------------------------------------
// K2: out0[b,n,o] = (1/32) * sum_i u[b,n,i,o]   (round 0: c uniform)
// Deterministic fixed-order tree. (validated round 2)
// ---------------------------------------------------------------------------
template<typename UT>
__global__ __launch_bounds__(256) void k_round0(
    const UT* __restrict__ u, float* __restrict__ out0)
{
  __shared__ float sPart[32*65];
  const int tid = threadIdx.x;
  const int bn  = blockIdx.x;          // b*32+n
  const int ip  = tid >> 3;
  const int o8  = tid & 7;
  const UT* base = u + (size_t)bn * (II*OO);
  float a[8];
  #pragma unroll
  for (int e = 0; e < 8; ++e) a[e] = 0.f;
  for (int i = ip; i < II; i += 32) {
    float t[8];
    load8u(base + (size_t)i*OO + o8*8, t);
    #pragma unroll
    for (int e = 0; e < 8; ++e) a[e] += t[e];
  }
  #pragma unroll
  for (int e = 0; e < 8; ++e) sPart[ip*65 + o8*8 + e] = a[e];
  for (int step = 16; step >= 1; step >>= 1) {
    __syncthreads();
    if (ip < step) {
      #pragma unroll
      for (int e = 0; e < 8; ++e)
        sPart[ip*65 + o8*8 + e] += sPart[(ip+step)*65 + o8*8 + e];
    }
  }
  __syncthreads();
  if (tid < 64) out0[(size_t)bn*OO + tid] = sPart[tid] * (1.f/32.f);
}

// ---------------------------------------------------------------------------
// K3a: c[b,i,n] = softmax_n( sum_o out_prev[b,n,o] * u[b,n,i,o] )
// Block = (b, batch of 16 i). Plain stores, fixed order -> deterministic.
// ---------------------------------------------------------------------------
template<typename UT>
__global__ __launch_bounds__(256) void k_logits(
    const UT* __restrict__ u, const float* __restrict__ out_prev,
    float* __restrict__ c)
{
  __shared__ float sOut[NN*OO];     // 2048
  __shared__ float sP[NN*9];        // partial dots, padded
  __shared__ float sLog[NN];
  const int tid = threadIdx.x;
  const int b   = blockIdx.x;
  const int i0  = blockIdx.y * 16;
  const int n   = tid >> 3;
  const int q   = tid & 7;

  for (int k = 0; k < 8; ++k) {
    int flat = tid + 256*k;
    sOut[flat] = out_prev[(size_t)b*NN*OO + flat];
  }
  __syncthreads();

  for (int ii = 0; ii < 16; ++ii) {
    int i = i0 + ii;
    // phase A: partial dot over o-chunk q
    {
      float t[8];
      load8u(u + (((size_t)b*NN + n)*II + i)*OO + q*8, t);
      float acc = 0.f;
      #pragma unroll
      for (int e = 0; e < 8; ++e) acc += t[e] * sOut[n*OO + q*8 + e];
      sP[n*9 + q] = acc;
    }
    __syncthreads();
    // phase B1: fixed-order sum over q -> logit[n]
    if (tid < NN) {
      float s = 0.f;
      #pragma unroll
      for (int qq = 0; qq < 8; ++qq) s += sP[tid*9 + qq];
      sLog[tid] = s;
    }
    __syncthreads();
    // phase B2: softmax over n (each of 32 threads reads all 32 logits)
    if (tid < NN) {
      float m = -1e30f;
      #pragma unroll
      for (int nn2 = 0; nn2 < NN; ++nn2) m = fmaxf(m, sLog[nn2]);
      float s = 0.f;
      #pragma unroll
      for (int nn2 = 0; nn2 < NN; ++nn2) s += __expf(sLog[nn2] - m);
      float cv = __expf(sLog[tid] - m) / s;
      c[((size_t)b*II + i)*NN + tid] = cv;
    }
    __syncthreads();   // protect sP/sLog before next i overwrites
  }
}

// ---------------------------------------------------------------------------
// K3b: out_next[b,n,o] = sum_i c[b,i,n] * u[b,n,i,o]
// Block per (b,n); fixed-order strided sum + LDS tree -> deterministic.
// ---------------------------------------------------------------------------
template<typename UT>
__global__ __launch_bounds__(256) void k_outs(
    const UT* __restrict__ u, const float* __restrict__ c,
    float* __restrict__ out_next)
{
  __shared__ float sPart[32*65];
  const int tid = threadIdx.x;
  const int bn  = blockIdx.x;          // b*32+n
  const int b   = bn >> 5;
  const int n   = bn & 31;
  const int ip  = tid >> 3;
  const int o8  = tid & 7;
  const UT* base = u + (size_t)bn * (II*OO);
  float a[8];
  #pragma unroll
  for (int e = 0; e < 8; ++e) a[e] = 0.f;
  for (int i = ip; i < II; i += 32) {
    float cv = c[((size_t)b*II + i)*NN + n];
    float t[8];
    load8u(base + (size_t)i*OO + o8*8, t);
    #pragma unroll
    for (int e = 0; e < 8; ++e) a[e] += cv * t[e];
  }
  #pragma unroll
  for (int e = 0; e < 8; ++e) sPart[ip*65 + o8*8 + e] = a[e];
  for (int step = 16; step >= 1; step >>= 1) {
    __syncthreads();
    if (ip < step) {
      #pragma unroll
      for (int e = 0; e < 8; ++e)
        sPart[ip*65 + o8*8 + e] += sPart[(ip+step)*65 + o8*8 + e];
    }
  }
  __syncthreads();
  if (tid < 64) out_next[(size_t)bn*OO + tid] = sPart[tid];
}

// ---------------------------------------------------------------------------
// K4: lengths[b,n] = sqrt(sum_o out2^2)
// ---------------------------------------------------------------------------
__global__ __launch_bounds__(256) void k_len(
    const float* __restrict__ out2, float* __restrict__ dout)
{
  int t = blockIdx.x*blockDim.x + threadIdx.x;
  if (t < BB*NN) {
    const float* p = out2 + (size_t)t*OO;
    float s = 0.f;
    #pragma unroll
    for (int o = 0; o < OO; ++o) { float f = p[o]; s += f*f; }
    dout[t] = sqrtf(s);
  }
}

template<typename UT>
static void run_pipeline(const float* x, const float* W, UT* u,
                         float* out0, float* out1, float* out2, float* c,
                         float* dout, hipStream_t stream)
{
  k_compute_u<UT><<<dim3(II, 4),  dim3(256), 0, stream>>>(x, W, u);
  k_round0<UT>  <<<dim3(BB*NN),   dim3(256), 0, stream>>>(u, out0);
  k_logits<UT>  <<<dim3(BB, II/16), dim3(256), 0, stream>>>(u, out0, c);
  k_outs<UT>    <<<dim3(BB*NN),   dim3(256), 0, stream>>>(u, c, out1);
  k_logits<UT>  <<<dim3(BB, II/16), dim3(256), 0, stream>>>(u, out1, c);
  k_outs<UT>    <<<dim3(BB*NN),   dim3(256), 0, stream>>>(u, c, out2);
  hipLaunchKernelGGL(k_len, dim3(8), dim3(256), 0, stream, out2, dout);
}

extern "C" void kernel_launch(void* const* d_in, const int* in_sizes, int n_in,
                              void* d_out, int out_size, void* d_ws, size_t ws_size,
                              hipStream_t stream)
{
  const float* x = (const float*)d_in[0];
  const float* W = (const float*)d_in[1];
  float* dout = (float*)d_out;

  const size_t U = (size_t)BB*NN*II*OO;   // 67,108,864 elements
  const size_t O = (size_t)BB*NN*OO;      // 131,072
  const size_t C = (size_t)BB*II*NN;      // 1,048,576

  const size_t need_f32 = U*4 + (3*O + C)*4;   // 256 MiB + 4.5 MiB
  if (ws_size >= need_f32) {
    float* u    = (float*)d_ws;
    float* out0 = u + U;
    float* out1 = out0 + O;
    float* out2 = out1 + O;
    float* c    = out2 + O;
    run_pipeline<float>(x, W, u, out0, out1, out2, c, dout, stream);
  } else {
    ushort_t* u = (ushort_t*)d_ws;
    float* out0 = (float*)((char*)d_ws + U*2);
    float* out1 = out0 + O;
    float* out2 = out1 + O;
    float* c    = out2 + O;
    run_pipeline<ushort_t>(x, W, u, out0, out1, out2, c, dout, stream);
  }
}